// Round 12
// baseline (520.103 us; speedup 1.0000x reference)
//
#include <hip/hip_runtime.h>
#include <math.h>

// ---------------------------------------------------------------------------
// MLPEncoder (NRI encoder) on MI355X — round 12:
//   - small chain merged: mlp_pq does input->L1->L2->P,Q in ONE kernel
//     (h1/h3 stay in LDS; 6 launches -> 2; no ha/hb global round trips).
//   - edge_mlp4: P/Q c=0 gathers issued before the stage barrier (hide L2
//     latency under GEMM1) + 1-deep c-pipeline for the rest.
//   Edge kernel structure otherwise = R10/R11 (128-row tiles).
// ---------------------------------------------------------------------------

typedef unsigned short ushort_t;
typedef __bf16 bf16x8 __attribute__((ext_vector_type(8)));
typedef float  f32x4  __attribute__((ext_vector_type(4)));

#define E_EDGES 9900
#define NNODE   100
#define HID     256
#define M_BIG   316800
#define M_SMALL 3200
#define NBLK2   (M_BIG / 128)   /* 2475 */

__device__ __forceinline__ float bf2f(ushort_t u) {
    union { unsigned int i; float f; } v; v.i = ((unsigned int)u) << 16; return v.f;
}
__device__ __forceinline__ ushort_t f2bf(float f) {
    union { float f; unsigned int i; } v; v.f = f;
    return (ushort_t)((v.i + 0x7fffu + ((v.i >> 16) & 1u)) >> 16);   // RNE
}
__device__ __forceinline__ float elu_f(float x) {
    return x > 0.f ? x : (__expf(x) - 1.f);
}

// ---- convert all weights to chan-major bf16 WT[col][K] --------------------
__global__ __launch_bounds__(256)
void wcvt_all(const float* __restrict__ s0, const float* __restrict__ s1,
              const float* __restrict__ s2, const float* __restrict__ s3,
              const float* __restrict__ s4, const float* __restrict__ s5,
              const float* __restrict__ s6, const float* __restrict__ s7,
              ushort_t* d0, ushort_t* d1, ushort_t* d2, ushort_t* d3,
              ushort_t* d4, ushort_t* d5, ushort_t* d6, ushort_t* d7)
{
    int bid = blockIdx.x;
    const float* S; ushort_t* D; int Kd, Kr, t;
    if      (bid < 16)  { S = s0; D = d0; Kd = 256; Kr = 200; t = bid; }
    else if (bid < 32)  { S = s1; D = d1; Kd = 256; Kr = 256; t = bid - 16; }
    else if (bid < 64)  { S = s2; D = d2; Kd = 512; Kr = 512; t = bid - 32; }
    else if (bid < 80)  { S = s3; D = d3; Kd = 256; Kr = 256; t = bid - 64; }
    else if (bid < 96)  { S = s4; D = d4; Kd = 256; Kr = 256; t = bid - 80; }
    else if (bid < 112) { S = s5; D = d5; Kd = 256; Kr = 256; t = bid - 96; }
    else if (bid < 160) { S = s6; D = d6; Kd = 768; Kr = 768; t = bid - 112; }
    else                { S = s7; D = d7; Kd = 256; Kr = 256; t = bid - 160; }
    int k0 = (t >> 2) * 64, c0 = (t & 3) * 64;
    __shared__ float Sh[64][65];
    int tid = threadIdx.x;
    #pragma unroll
    for (int i = 0; i < 16; ++i) {
        int idx = tid + i * 256;
        int kk = idx >> 6, cc = idx & 63;
        Sh[kk][cc] = (k0 + kk < Kr) ? S[(size_t)(k0 + kk) * 256 + c0 + cc] : 0.f;
    }
    __syncthreads();
    int col = tid & 63;
    int kb  = (tid >> 6) * 16;
    ushort_t* dst = D + (size_t)(c0 + col) * Kd + k0 + kb;
    #pragma unroll
    for (int jj = 0; jj < 4; ++jj) {
        ushort4 u;
        u.x = f2bf(Sh[kb + 4 * jj + 0][col]);
        u.y = f2bf(Sh[kb + 4 * jj + 1][col]);
        u.z = f2bf(Sh[kb + 4 * jj + 2][col]);
        u.w = f2bf(Sh[kb + 4 * jj + 3][col]);
        *(ushort4*)(dst + 4 * jj) = u;
    }
}

// ---- 2-row-tile GEMM helper over a 32x264 LDS tile ------------------------
__device__ __forceinline__ void gemm32(const ushort_t S[32][264],
                                       const ushort_t* __restrict__ WT,
                                       int wstr, int kcn,
                                       int w, int ln15, int klane,
                                       f32x4 acc[2][4])
{
    #pragma unroll
    for (int r = 0; r < 2; ++r)
        #pragma unroll
        for (int c = 0; c < 4; ++c)
            acc[r][c][0] = acc[r][c][1] = acc[r][c][2] = acc[r][c][3] = 0.f;
    int wch[4];
    #pragma unroll
    for (int c = 0; c < 4; ++c) wch[c] = (w * 64 + 16 * c + ln15) * wstr;
    bf16x8 wf0[4];
    #pragma unroll
    for (int c = 0; c < 4; ++c)
        wf0[c] = *(const bf16x8*)(WT + wch[c] + klane);
    for (int kc = 0; kc < kcn; ++kc) {
        bf16x8 wf1[4];
        if (kc + 1 < kcn) {
            #pragma unroll
            for (int c = 0; c < 4; ++c)
                wf1[c] = *(const bf16x8*)(WT + wch[c] + (kc + 1) * 32 + klane);
        }
        bf16x8 af[2];
        #pragma unroll
        for (int r = 0; r < 2; ++r)
            af[r] = *(const bf16x8*)&S[16 * r + ln15][kc * 32 + klane];
        #pragma unroll
        for (int r = 0; r < 2; ++r)
            #pragma unroll
            for (int c = 0; c < 4; ++c)
                acc[r][c] = __builtin_amdgcn_mfma_f32_16x16x32_bf16(wf0[c], af[r], acc[r][c], 0, 0, 0);
        #pragma unroll
        for (int c = 0; c < 4; ++c) wf0[c] = wf1[c];
    }
}

__device__ __forceinline__ void park32(ushort_t D[32][264], f32x4 acc[2][4],
                                       const float* __restrict__ bias,
                                       int act, int w, int ln15, int q)
{
    #pragma unroll
    for (int c = 0; c < 4; ++c) {
        float4 bv = bias ? *(const float4*)&bias[w * 64 + 16 * c + 4 * q]
                         : make_float4(0.f, 0.f, 0.f, 0.f);
        #pragma unroll
        for (int r = 0; r < 2; ++r) {
            float o0 = acc[r][c][0] + bv.x;
            float o1 = acc[r][c][1] + bv.y;
            float o2 = acc[r][c][2] + bv.z;
            float o3 = acc[r][c][3] + bv.w;
            if (act) { o0 = elu_f(o0); o1 = elu_f(o1); o2 = elu_f(o2); o3 = elu_f(o3); }
            ushort4 u;
            u.x = f2bf(o0); u.y = f2bf(o1); u.z = f2bf(o2); u.w = f2bf(o3);
            *(ushort4*)&D[16 * r + ln15][w * 64 + 16 * c + 4 * q] = u;
        }
    }
}

// ---- merged small chain: X[3200,K] -> L1 -> L2 -> P,Q  (one kernel) -------
__global__ __launch_bounds__(256, 4)
void mlp_pq(const float* __restrict__ Xf, int Kreal, int kcN, float xscale,
            const ushort_t* __restrict__ W1T, const float* __restrict__ b1,
            const ushort_t* __restrict__ W2T, const float* __restrict__ b2,
            const ushort_t* __restrict__ WPT, int wsPQ,
            const float* __restrict__ bP, ushort_t* __restrict__ Pout,
            const ushort_t* __restrict__ WQT, ushort_t* __restrict__ Qout)
{
    __shared__ ushort_t Abuf[32][264];
    __shared__ ushort_t Bbuf[32][264];
    const int tid = threadIdx.x;
    const int w = tid >> 6;
    const int l = tid & 63;
    const int ln15 = l & 15;
    const int q = l >> 4;
    const int klane = 8 * q;
    const int Rbase = blockIdx.x * 32;

    // stage X (fp32 -> bf16, xscale folded in)
    {
        int row = tid >> 3, seg = tid & 7;
        if (seg < kcN) {
            ushort_t tmp[32];
            const float* src = Xf + (size_t)(Rbase + row) * Kreal + seg * 32;
            #pragma unroll
            for (int u = 0; u < 32; ++u)
                tmp[u] = (seg * 32 + u < Kreal) ? f2bf(src[u] * xscale) : (ushort_t)0;
            #pragma unroll
            for (int u = 0; u < 4; ++u)
                *(uint4*)&Abuf[row][seg * 32 + u * 8] = *(uint4*)&tmp[u * 8];
        }
    }
    __syncthreads();

    f32x4 acc[2][4];
    // L1: h1a = ELU(A @ W1T + b1) -> B
    gemm32(Abuf, W1T, 256, kcN, w, ln15, klane, acc);
    park32(Bbuf, acc, b1, 1, w, ln15, q);
    __syncthreads();
    // L2: h = ELU(B @ W2T + b2) -> A
    gemm32(Bbuf, W2T, 256, 8, w, ln15, klane, acc);
    park32(Abuf, acc, b2, 1, w, ln15, q);
    __syncthreads();
    // P = A @ WPT + bP -> B
    gemm32(Abuf, WPT, wsPQ, 8, w, ln15, klane, acc);
    park32(Bbuf, acc, bP, 0, w, ln15, q);
    __syncthreads();
    // Q GEMM (reads A) + write P (reads B) — both read-only this phase
    f32x4 acq[2][4];
    gemm32(Abuf, WQT, wsPQ, 8, w, ln15, klane, acq);
    #pragma unroll
    for (int m = 0; m < 4; ++m) {
        int ch = tid + m * 256;
        int row = ch >> 5;
        int o = (ch & 31) * 8;
        *(uint4*)&Pout[(size_t)(Rbase + row) * 256 + o] = *(const uint4*)&Bbuf[row][o];
    }
    __syncthreads();
    park32(Bbuf, acq, nullptr, 0, w, ln15, q);
    __syncthreads();
    #pragma unroll
    for (int m = 0; m < 4; ++m) {
        int ch = tid + m * 256;
        int row = ch >> 5;
        int o = (ch & 31) * 8;
        *(uint4*)&Qout[(size_t)(Rbase + row) * 256 + o] = *(const uint4*)&Bbuf[row][o];
    }
}

// ---- edge kernel A (MLP2), 128-row tile (unchanged from R10/R11) ----------
__global__ __launch_bounds__(256, 2)
void edge_mlp2(const ushort_t* __restrict__ Pb, const ushort_t* __restrict__ Qb,
               const ushort_t* __restrict__ W2T,
               const float* __restrict__ b2,
               ushort_t* __restrict__ Y, float* __restrict__ aux)
{
    __shared__ ushort_t As[128][264];
    const int tid = threadIdx.x;
    const int w = tid >> 6;
    const int l = tid & 63;
    const int ln15 = l & 15;
    const int q = l >> 4;
    const int klane = 8 * q;
    const int Rbase = blockIdx.x * 128;

    for (int h = 0; h < 2; ++h) {
        int row = (tid >> 2) + 64 * h;
        int R = Rbase + row;
        int b = R / E_EDGES;
        int e = R - b * E_EDGES;
        int i = e / 99;
        int k = e - 99 * i;
        int j = k + (k >= i ? 1 : 0);
        const ushort_t* prow = Pb + (size_t)(b * NNODE + j) * HID;
        const ushort_t* qrow = Qb + (size_t)(b * NNODE + i) * HID;
        int off = (tid & 3) * 8;
        uint4 pv[8], qv[8];
        #pragma unroll
        for (int u = 0; u < 8; ++u) {
            int o = off + u * 32;
            pv[u] = *(const uint4*)(prow + o);
            qv[u] = *(const uint4*)(qrow + o);
        }
        #pragma unroll
        for (int u = 0; u < 8; ++u) {
            int o = off + u * 32;
            union { uint4 v; ushort_t s[8]; } pu, qu, hu;
            pu.v = pv[u]; qu.v = qv[u];
            #pragma unroll
            for (int x = 0; x < 8; ++x)
                hu.s[x] = f2bf(elu_f(bf2f(pu.s[x]) + bf2f(qu.s[x])));
            *(uint4*)&As[row][o] = hu.v;
        }
    }
    __syncthreads();

    f32x4 acc[8][4];
    #pragma unroll
    for (int r = 0; r < 8; ++r)
        #pragma unroll
        for (int c = 0; c < 4; ++c)
            acc[r][c][0] = acc[r][c][1] = acc[r][c][2] = acc[r][c][3] = 0.f;
    int wch[4];
    #pragma unroll
    for (int c = 0; c < 4; ++c) wch[c] = (w * 64 + 16 * c + ln15) * 256;
    {
        bf16x8 wf0[4];
        #pragma unroll
        for (int c = 0; c < 4; ++c)
            wf0[c] = *(const bf16x8*)(W2T + wch[c] + klane);
        #pragma unroll
        for (int kc = 0; kc < 8; ++kc) {
            bf16x8 wf1[4];
            if (kc < 7) {
                #pragma unroll
                for (int c = 0; c < 4; ++c)
                    wf1[c] = *(const bf16x8*)(W2T + wch[c] + (kc + 1) * 32 + klane);
            }
            bf16x8 af[8];
            #pragma unroll
            for (int r = 0; r < 8; ++r)
                af[r] = *(const bf16x8*)&As[16 * r + ln15][kc * 32 + klane];
            #pragma unroll
            for (int r = 0; r < 8; ++r)
                #pragma unroll
                for (int c = 0; c < 4; ++c)
                    acc[r][c] = __builtin_amdgcn_mfma_f32_16x16x32_bf16(wf0[c], af[r], acc[r][c], 0, 0, 0);
            #pragma unroll
            for (int c = 0; c < 4; ++c) wf0[c] = wf1[c];
        }
    }
    __syncthreads();

    #pragma unroll
    for (int c = 0; c < 4; ++c) {
        float4 bv = *(const float4*)&b2[w * 64 + 16 * c + 4 * q];
        #pragma unroll
        for (int r = 0; r < 8; ++r) {
            ushort4 u;
            u.x = f2bf(elu_f(acc[r][c][0] + bv.x));
            u.y = f2bf(elu_f(acc[r][c][1] + bv.y));
            u.z = f2bf(elu_f(acc[r][c][2] + bv.z));
            u.w = f2bf(elu_f(acc[r][c][3] + bv.w));
            *(ushort4*)&As[16 * r + ln15][w * 64 + 16 * c + 4 * q] = u;
        }
    }
    __syncthreads();

    #pragma unroll
    for (int m = 0; m < 16; ++m) {
        int ch = tid + m * 256;
        int row = ch >> 5;
        int o = (ch & 31) * 8;
        *(uint4*)&Y[((size_t)(Rbase + row)) * 256 + o] = *(const uint4*)&As[row][o];
    }

    if (tid < 64) {
        int c4 = tid * 4;
        int bn = Rbase / 99;
        int left = 99 - (Rbase - bn * 99);
        float s[4] = {0.f, 0.f, 0.f, 0.f};
        for (int r = 0; r < 128; ++r) {
            union { ushort4 v; ushort_t e[4]; } u;
            u.v = *(const ushort4*)&As[r][c4];
            #pragma unroll
            for (int g = 0; g < 4; ++g) s[g] += bf2f(u.e[g]);
            if (--left == 0) {
                #pragma unroll
                for (int g = 0; g < 4; ++g) {
                    atomicAdd(&aux[(size_t)bn * 256 + c4 + g], s[g]);
                    s[g] = 0.f;
                }
                ++bn; left = 99;
            }
        }
        #pragma unroll
        for (int g = 0; g < 4; ++g)
            atomicAdd(&aux[(size_t)bn * 256 + c4 + g], s[g]);
    }
}

// ---- edge kernel B (MLP4), 128-row tile + early P/Q prefetch --------------
__global__ __launch_bounds__(256, 2)
void edge_mlp4(const ushort_t* __restrict__ Pb, const ushort_t* __restrict__ Qb,
               const ushort_t* __restrict__ X2,
               const ushort_t* __restrict__ WaT, int wsA,
               const ushort_t* __restrict__ WbT, int wsB,
               const float* __restrict__ b2,
               ushort_t* __restrict__ Y, ushort_t* __restrict__ pstat)
{
    __shared__ ushort_t As[128][264];
    const int tid = threadIdx.x;
    const int w = tid >> 6;
    const int l = tid & 63;
    const int ln15 = l & 15;
    const int q = l >> 4;
    const int klane = 8 * q;
    const int Rbase = blockIdx.x * 128;

    // stage x2 tile (issued first: the HBM-heavy loads)
    uint4 xv[2][8];
    #pragma unroll
    for (int h = 0; h < 2; ++h) {
        int row = (tid >> 2) + 64 * h;
        const ushort_t* xrow = X2 + (size_t)(Rbase + row) * 256;
        int off = (tid & 3) * 8;
        #pragma unroll
        for (int u = 0; u < 8; ++u) xv[h][u] = *(const uint4*)(xrow + off + u * 32);
    }

    // gather offsets + c=0 P/Q prefetch (in flight through GEMM1)
    int oP[8], oQ[8];
    #pragma unroll
    for (int r = 0; r < 8; ++r) {
        int R = Rbase + 16 * r + ln15;
        int b = R / E_EDGES;
        int e = R - b * E_EDGES;
        int i = e / 99;
        int k = e - 99 * i;
        int j = k + (k >= i ? 1 : 0);
        oP[r] = (b * NNODE + j) * HID;
        oQ[r] = (b * NNODE + i) * HID;
    }
    ushort4 pv0[8], qv0[8];
    {
        int ch0 = w * 64 + 4 * q;
        #pragma unroll
        for (int r = 0; r < 8; ++r) {
            pv0[r] = *(const ushort4*)(Pb + oP[r] + ch0);
            qv0[r] = *(const ushort4*)(Qb + oQ[r] + ch0);
        }
    }

    #pragma unroll
    for (int h = 0; h < 2; ++h) {
        int row = (tid >> 2) + 64 * h;
        int off = (tid & 3) * 8;
        #pragma unroll
        for (int u = 0; u < 8; ++u) *(uint4*)&As[row][off + u * 32] = xv[h][u];
    }
    __syncthreads();

    f32x4 acc[8][4];
    int wchA[4], wchB[4];
    #pragma unroll
    for (int c = 0; c < 4; ++c) {
        wchA[c] = (w * 64 + 16 * c + ln15) * wsA;
        wchB[c] = (w * 64 + 16 * c + ln15) * wsB;
    }

    // L1 GEMM: acc = x2tile @ W4a3
    #pragma unroll
    for (int r = 0; r < 8; ++r)
        #pragma unroll
        for (int c = 0; c < 4; ++c)
            acc[r][c][0] = acc[r][c][1] = acc[r][c][2] = acc[r][c][3] = 0.f;
    {
        bf16x8 wf0[4];
        #pragma unroll
        for (int c = 0; c < 4; ++c)
            wf0[c] = *(const bf16x8*)(WaT + wchA[c] + klane);
        #pragma unroll
        for (int kc = 0; kc < 8; ++kc) {
            bf16x8 wf1[4];
            if (kc < 7) {
                #pragma unroll
                for (int c = 0; c < 4; ++c)
                    wf1[c] = *(const bf16x8*)(WaT + wchA[c] + (kc + 1) * 32 + klane);
            }
            bf16x8 af[8];
            #pragma unroll
            for (int r = 0; r < 8; ++r)
                af[r] = *(const bf16x8*)&As[16 * r + ln15][kc * 32 + klane];
            #pragma unroll
            for (int r = 0; r < 8; ++r)
                #pragma unroll
                for (int c = 0; c < 4; ++c)
                    acc[r][c] = __builtin_amdgcn_mfma_f32_16x16x32_bf16(wf0[c], af[r], acc[r][c], 0, 0, 0);
            #pragma unroll
            for (int c = 0; c < 4; ++c) wf0[c] = wf1[c];
        }
    }
    __syncthreads();

    // hidden = ELU(acc + P[j] + Q[i]) -> As  (1-deep c-pipeline, pv0 prefetched)
    #pragma unroll
    for (int c = 0; c < 4; ++c) {
        ushort4 pv1[8], qv1[8];
        if (c < 3) {
            int chn = w * 64 + 16 * (c + 1) + 4 * q;
            #pragma unroll
            for (int r = 0; r < 8; ++r) {
                pv1[r] = *(const ushort4*)(Pb + oP[r] + chn);
                qv1[r] = *(const ushort4*)(Qb + oQ[r] + chn);
            }
        }
        int ch = w * 64 + 16 * c + 4 * q;
        #pragma unroll
        for (int r = 0; r < 8; ++r) {
            union { ushort4 v; ushort_t s[4]; } pu, qu;
            pu.v = pv0[r]; qu.v = qv0[r];
            ushort4 u;
            u.x = f2bf(elu_f(acc[r][c][0] + bf2f(pu.s[0]) + bf2f(qu.s[0])));
            u.y = f2bf(elu_f(acc[r][c][1] + bf2f(pu.s[1]) + bf2f(qu.s[1])));
            u.z = f2bf(elu_f(acc[r][c][2] + bf2f(pu.s[2]) + bf2f(qu.s[2])));
            u.w = f2bf(elu_f(acc[r][c][3] + bf2f(pu.s[3]) + bf2f(qu.s[3])));
            *(ushort4*)&As[16 * r + ln15][ch] = u;
        }
        #pragma unroll
        for (int r = 0; r < 8; ++r) { pv0[r] = pv1[r]; qv0[r] = qv1[r]; }
    }
    __syncthreads();

    // L2 GEMM: acc = hidden @ W4b
    #pragma unroll
    for (int r = 0; r < 8; ++r)
        #pragma unroll
        for (int c = 0; c < 4; ++c)
            acc[r][c][0] = acc[r][c][1] = acc[r][c][2] = acc[r][c][3] = 0.f;
    {
        bf16x8 wf0[4];
        #pragma unroll
        for (int c = 0; c < 4; ++c)
            wf0[c] = *(const bf16x8*)(WbT + wchB[c] + klane);
        #pragma unroll
        for (int kc = 0; kc < 8; ++kc) {
            bf16x8 wf1[4];
            if (kc < 7) {
                #pragma unroll
                for (int c = 0; c < 4; ++c)
                    wf1[c] = *(const bf16x8*)(WbT + wchB[c] + (kc + 1) * 32 + klane);
            }
            bf16x8 af[8];
            #pragma unroll
            for (int r = 0; r < 8; ++r)
                af[r] = *(const bf16x8*)&As[16 * r + ln15][kc * 32 + klane];
            #pragma unroll
            for (int r = 0; r < 8; ++r)
                #pragma unroll
                for (int c = 0; c < 4; ++c)
                    acc[r][c] = __builtin_amdgcn_mfma_f32_16x16x32_bf16(wf0[c], af[r], acc[r][c], 0, 0, 0);
            #pragma unroll
            for (int c = 0; c < 4; ++c) wf0[c] = wf1[c];
        }
    }
    __syncthreads();

    // x4 = ELU(acc + b2) -> As park
    #pragma unroll
    for (int c = 0; c < 4; ++c) {
        float4 bv = *(const float4*)&b2[w * 64 + 16 * c + 4 * q];
        #pragma unroll
        for (int r = 0; r < 8; ++r) {
            ushort4 u;
            u.x = f2bf(elu_f(acc[r][c][0] + bv.x));
            u.y = f2bf(elu_f(acc[r][c][1] + bv.y));
            u.z = f2bf(elu_f(acc[r][c][2] + bv.z));
            u.w = f2bf(elu_f(acc[r][c][3] + bv.w));
            *(ushort4*)&As[16 * r + ln15][w * 64 + 16 * c + 4 * q] = u;
        }
    }
    __syncthreads();

    #pragma unroll
    for (int m = 0; m < 16; ++m) {
        int ch = tid + m * 256;
        int row = ch >> 5;
        int o = (ch & 31) * 8;
        *(uint4*)&Y[((size_t)(Rbase + row)) * 256 + o] = *(const uint4*)&As[row][o];
    }

    if (tid < 64) {
        int c4 = tid * 4;
        float s[4] = {0.f, 0.f, 0.f, 0.f};
        float qq[4] = {0.f, 0.f, 0.f, 0.f};
        for (int r = 0; r < 128; ++r) {
            union { ushort4 v; ushort_t e[4]; } u;
            u.v = *(const ushort4*)&As[r][c4];
            #pragma unroll
            for (int g = 0; g < 4; ++g) {
                float v = bf2f(u.e[g]);
                s[g] += v;
                qq[g] = fmaf(v, v, qq[g]);
            }
        }
        size_t base = (size_t)blockIdx.x * 512;
        ushort4 us, uq;
        us.x = f2bf(s[0]);  us.y = f2bf(s[1]);  us.z = f2bf(s[2]);  us.w = f2bf(s[3]);
        uq.x = f2bf(qq[0]); uq.y = f2bf(qq[1]); uq.z = f2bf(qq[2]); uq.w = f2bf(qq[3]);
        *(ushort4*)&pstat[base + c4]       = us;
        *(ushort4*)&pstat[base + 256 + c4] = uq;
    }
}

// ---- reduce per-block partials -> stats -----------------------------------
__global__ __launch_bounds__(256)
void reduce_stats(const ushort_t* __restrict__ pstat, float* __restrict__ stats)
{
    int c = threadIdx.x;
    float s = 0.f, q = 0.f;
    for (int b = blockIdx.x; b < NBLK2; b += 64) {
        size_t base = (size_t)b * 512;
        s += bf2f(pstat[base + c]);
        q += bf2f(pstat[base + 256 + c]);
    }
    atomicAdd(&stats[c], s);
    atomicAdd(&stats[256 + c], q);
}

// ---- fold BN + fc into Wfold[256][2], bfold[2] ----------------------------
__global__ __launch_bounds__(256)
void fold_kernel(const float* __restrict__ stats,
                 const float* __restrict__ gamma, const float* __restrict__ beta,
                 const float* __restrict__ fcW, const float* __restrict__ fcb,
                 float* __restrict__ fold)
{
    __shared__ float red0[256], red1[256];
    int c = threadIdx.x;
    float mean  = stats[c] * (1.f / M_BIG);
    float var   = stats[256 + c] * (1.f / M_BIG) - mean * mean;
    float inv   = rsqrtf(var + 1e-5f);
    float scale = inv * gamma[c];
    float sh    = beta[c] - mean * scale;
    float w0 = fcW[c * 2 + 0], w1 = fcW[c * 2 + 1];
    fold[c * 2 + 0] = scale * w0;
    fold[c * 2 + 1] = scale * w1;
    red0[c] = sh * w0;
    red1[c] = sh * w1;
    __syncthreads();
    for (int off = 128; off > 0; off >>= 1) {
        if (c < off) { red0[c] += red0[c + off]; red1[c] += red1[c + off]; }
        __syncthreads();
    }
    if (c == 0) {
        fold[512] = red0[0] + fcb[0];
        fold[513] = red1[0] + fcb[1];
    }
}

// ---- final: out[R][2] = x4_row . Wfold + bfold ----------------------------
__global__ __launch_bounds__(256)
void final_kernel(const ushort_t* __restrict__ x4, const float* __restrict__ fold,
                  float* __restrict__ out)
{
    int tid  = threadIdx.x;
    int l32  = tid & 31;
    int g    = tid >> 5;
    int R = blockIdx.x * 8 + g;
    int c0 = l32 * 8;
    union { uint4 qv; ushort_t s[8]; } u;
    u.qv = *(const uint4*)(x4 + (size_t)R * 256 + c0);
    float a0 = 0.f, a1 = 0.f;
    #pragma unroll
    for (int j = 0; j < 8; ++j) {
        float v = bf2f(u.s[j]);
        a0 = fmaf(v, fold[(c0 + j) * 2 + 0], a0);
        a1 = fmaf(v, fold[(c0 + j) * 2 + 1], a1);
    }
    #pragma unroll
    for (int off = 16; off > 0; off >>= 1) {
        a0 += __shfl_down(a0, off);
        a1 += __shfl_down(a1, off);
    }
    if (l32 == 0) {
        out[(size_t)R * 2 + 0] = a0 + fold[512];
        out[(size_t)R * 2 + 1] = a1 + fold[513];
    }
}

extern "C" void kernel_launch(void* const* d_in, const int* in_sizes, int n_in,
                              void* d_out, int out_size, void* d_ws, size_t ws_size,
                              hipStream_t stream)
{
    (void)in_sizes; (void)n_in; (void)out_size; (void)ws_size;

    const float* inputs = (const float*)d_in[0];
    const float* m1W1 = (const float*)d_in[3];
    const float* m1b1 = (const float*)d_in[4];
    const float* m1W2 = (const float*)d_in[5];
    const float* m1b2 = (const float*)d_in[6];
    const float* m2W1 = (const float*)d_in[7];
    const float* m2b1 = (const float*)d_in[8];
    const float* m2W2 = (const float*)d_in[9];
    const float* m2b2 = (const float*)d_in[10];
    const float* m3W1 = (const float*)d_in[11];
    const float* m3b1 = (const float*)d_in[12];
    const float* m3W2 = (const float*)d_in[13];
    const float* m3b2 = (const float*)d_in[14];
    const float* m4W1 = (const float*)d_in[15];
    const float* m4b1 = (const float*)d_in[16];
    const float* m4W2 = (const float*)d_in[17];
    const float* m4b2 = (const float*)d_in[18];
    const float* gamma = (const float*)d_in[19];
    const float* beta  = (const float*)d_in[20];
    const float* fcW   = (const float*)d_in[21];
    const float* fcb   = (const float*)d_in[22];
    float* out = (float*)d_out;

    // ---- workspace layout ----
    char* ws = (char*)d_ws;
    const size_t BIGB = (size_t)M_BIG * 256 * 2;      // 162,201,600
    const size_t HB   = (size_t)M_SMALL * 256 * 2;    // 1,638,400
    const size_t SM4  = (size_t)M_SMALL * 256 * 4;    // 3,276,800
    ushort_t* bigX     = (ushort_t*)ws;                         // x2 then x4
    ushort_t* pstat    = (ushort_t*)(ws + BIGB);                // 2.53 MB
    float*    incoming = (float*)(ws + BIGB + 2 * HB);
    ushort_t* Pbuf     = (ushort_t*)(ws + BIGB + 2 * HB + SM4);
    ushort_t* Qbuf     = (ushort_t*)(ws + BIGB + 3 * HB + SM4);
    float*    stats    = (float*)(ws + BIGB + 4 * HB + SM4);
    float*    fold     = stats + 512;
    ushort_t* w1t      = (ushort_t*)(ws + BIGB + 4 * HB + SM4 + 8192);
    ushort_t* w1bt     = w1t  + 256 * 256;
    ushort_t* w2pt     = w1bt + 256 * 256;     // [256][512]
    ushort_t* w2t      = w2pt + 256 * 512;
    ushort_t* w3at     = w2t  + 256 * 256;
    ushort_t* w3bt     = w3at + 256 * 256;
    ushort_t* w4pt     = w3bt + 256 * 256;     // [256][768]
    ushort_t* w4bt     = w4pt + 256 * 768;

    hipMemsetAsync(stats, 0, 2048, stream);
    hipMemsetAsync(incoming, 0, SM4, stream);

    dim3 blk(256);
    wcvt_all<<<176, blk, 0, stream>>>(m1W1, m1W2, m2W1, m2W2, m3W1, m3W2, m4W1, m4W2,
                                      w1t, w1bt, w2pt, w2t, w3at, w3bt, w4pt, w4bt);
    // MLP1 + PQ2 (h1 never leaves LDS)
    mlp_pq<<<100, blk, 0, stream>>>(inputs, 200, 7, 1.f,
                                    w1t, m1b1, w1bt, m1b2,
                                    w2pt, 512, m2b1, Pbuf,
                                    w2pt + 256, Qbuf);
    // edge MLP2 -> x2 + e2n sums
    edge_mlp2<<<NBLK2, blk, 0, stream>>>(Pbuf, Qbuf, w2t, m2b2, bigX, incoming);
    // MLP3 + PQ4
    mlp_pq<<<100, blk, 0, stream>>>(incoming, 256, 8, 1.f / 9900.f,
                                    w3at, m3b1, w3bt, m3b2,
                                    w4pt, 768, m4b1, Pbuf,
                                    w4pt + 256, Qbuf);
    // edge MLP4 (skip weight = w4pt cols 512.., stride 768)
    edge_mlp4<<<NBLK2, blk, 0, stream>>>(Pbuf, Qbuf, bigX,
                                         w4pt + 512, 768, w4bt, 256,
                                         m4b2, bigX, pstat);
    reduce_stats<<<64, blk, 0, stream>>>(pstat, stats);
    fold_kernel<<<1, blk, 0, stream>>>(stats, gamma, beta, fcW, fcb, fold);
    final_kernel<<<M_BIG / 8, blk, 0, stream>>>(bigX, fold, out);
}

// Round 13
// 494.508 us; speedup vs baseline: 1.0518x; 1.0518x over previous
//
#include <hip/hip_runtime.h>
#include <math.h>

// ---------------------------------------------------------------------------
// MLPEncoder (NRI encoder) on MI355X — round 13: column-split edge waves.
//   Edge kernels: 512 thr / 8 waves; wave owns 32 cols x 128 rows
//   (acc 8x2 = 64 AGPR) -> regs/wave ~110 -> 4 waves/SIMD (was 2) with the
//   same 128-row tile + W-amortization. R12's x2 early-prefetch reverted.
//   Small chain (mlp_pq), wcvt, reduce/fold/final = R12.
// ---------------------------------------------------------------------------

typedef unsigned short ushort_t;
typedef __bf16 bf16x8 __attribute__((ext_vector_type(8)));
typedef float  f32x4  __attribute__((ext_vector_type(4)));

#define E_EDGES 9900
#define NNODE   100
#define HID     256
#define M_BIG   316800
#define M_SMALL 3200
#define NBLK2   (M_BIG / 128)   /* 2475 */

__device__ __forceinline__ float bf2f(ushort_t u) {
    union { unsigned int i; float f; } v; v.i = ((unsigned int)u) << 16; return v.f;
}
__device__ __forceinline__ ushort_t f2bf(float f) {
    union { float f; unsigned int i; } v; v.f = f;
    return (ushort_t)((v.i + 0x7fffu + ((v.i >> 16) & 1u)) >> 16);   // RNE
}
__device__ __forceinline__ float elu_f(float x) {
    return x > 0.f ? x : (__expf(x) - 1.f);
}

// ---- convert all weights to chan-major bf16 WT[col][K] --------------------
__global__ __launch_bounds__(256)
void wcvt_all(const float* __restrict__ s0, const float* __restrict__ s1,
              const float* __restrict__ s2, const float* __restrict__ s3,
              const float* __restrict__ s4, const float* __restrict__ s5,
              const float* __restrict__ s6, const float* __restrict__ s7,
              ushort_t* d0, ushort_t* d1, ushort_t* d2, ushort_t* d3,
              ushort_t* d4, ushort_t* d5, ushort_t* d6, ushort_t* d7)
{
    int bid = blockIdx.x;
    const float* S; ushort_t* D; int Kd, Kr, t;
    if      (bid < 16)  { S = s0; D = d0; Kd = 256; Kr = 200; t = bid; }
    else if (bid < 32)  { S = s1; D = d1; Kd = 256; Kr = 256; t = bid - 16; }
    else if (bid < 64)  { S = s2; D = d2; Kd = 512; Kr = 512; t = bid - 32; }
    else if (bid < 80)  { S = s3; D = d3; Kd = 256; Kr = 256; t = bid - 64; }
    else if (bid < 96)  { S = s4; D = d4; Kd = 256; Kr = 256; t = bid - 80; }
    else if (bid < 112) { S = s5; D = d5; Kd = 256; Kr = 256; t = bid - 96; }
    else if (bid < 160) { S = s6; D = d6; Kd = 768; Kr = 768; t = bid - 112; }
    else                { S = s7; D = d7; Kd = 256; Kr = 256; t = bid - 160; }
    int k0 = (t >> 2) * 64, c0 = (t & 3) * 64;
    __shared__ float Sh[64][65];
    int tid = threadIdx.x;
    #pragma unroll
    for (int i = 0; i < 16; ++i) {
        int idx = tid + i * 256;
        int kk = idx >> 6, cc = idx & 63;
        Sh[kk][cc] = (k0 + kk < Kr) ? S[(size_t)(k0 + kk) * 256 + c0 + cc] : 0.f;
    }
    __syncthreads();
    int col = tid & 63;
    int kb  = (tid >> 6) * 16;
    ushort_t* dst = D + (size_t)(c0 + col) * Kd + k0 + kb;
    #pragma unroll
    for (int jj = 0; jj < 4; ++jj) {
        ushort4 u;
        u.x = f2bf(Sh[kb + 4 * jj + 0][col]);
        u.y = f2bf(Sh[kb + 4 * jj + 1][col]);
        u.z = f2bf(Sh[kb + 4 * jj + 2][col]);
        u.w = f2bf(Sh[kb + 4 * jj + 3][col]);
        *(ushort4*)(dst + 4 * jj) = u;
    }
}

// ---- 2-row-tile GEMM helper over a 32x264 LDS tile (small chain) ----------
__device__ __forceinline__ void gemm32(const ushort_t S[32][264],
                                       const ushort_t* __restrict__ WT,
                                       int wstr, int kcn,
                                       int w, int ln15, int klane,
                                       f32x4 acc[2][4])
{
    #pragma unroll
    for (int r = 0; r < 2; ++r)
        #pragma unroll
        for (int c = 0; c < 4; ++c)
            acc[r][c][0] = acc[r][c][1] = acc[r][c][2] = acc[r][c][3] = 0.f;
    int wch[4];
    #pragma unroll
    for (int c = 0; c < 4; ++c) wch[c] = (w * 64 + 16 * c + ln15) * wstr;
    bf16x8 wf0[4];
    #pragma unroll
    for (int c = 0; c < 4; ++c)
        wf0[c] = *(const bf16x8*)(WT + wch[c] + klane);
    for (int kc = 0; kc < kcn; ++kc) {
        bf16x8 wf1[4];
        if (kc + 1 < kcn) {
            #pragma unroll
            for (int c = 0; c < 4; ++c)
                wf1[c] = *(const bf16x8*)(WT + wch[c] + (kc + 1) * 32 + klane);
        }
        bf16x8 af[2];
        #pragma unroll
        for (int r = 0; r < 2; ++r)
            af[r] = *(const bf16x8*)&S[16 * r + ln15][kc * 32 + klane];
        #pragma unroll
        for (int r = 0; r < 2; ++r)
            #pragma unroll
            for (int c = 0; c < 4; ++c)
                acc[r][c] = __builtin_amdgcn_mfma_f32_16x16x32_bf16(wf0[c], af[r], acc[r][c], 0, 0, 0);
        #pragma unroll
        for (int c = 0; c < 4; ++c) wf0[c] = wf1[c];
    }
}

__device__ __forceinline__ void park32(ushort_t D[32][264], f32x4 acc[2][4],
                                       const float* __restrict__ bias,
                                       int act, int w, int ln15, int q)
{
    #pragma unroll
    for (int c = 0; c < 4; ++c) {
        float4 bv = bias ? *(const float4*)&bias[w * 64 + 16 * c + 4 * q]
                         : make_float4(0.f, 0.f, 0.f, 0.f);
        #pragma unroll
        for (int r = 0; r < 2; ++r) {
            float o0 = acc[r][c][0] + bv.x;
            float o1 = acc[r][c][1] + bv.y;
            float o2 = acc[r][c][2] + bv.z;
            float o3 = acc[r][c][3] + bv.w;
            if (act) { o0 = elu_f(o0); o1 = elu_f(o1); o2 = elu_f(o2); o3 = elu_f(o3); }
            ushort4 u;
            u.x = f2bf(o0); u.y = f2bf(o1); u.z = f2bf(o2); u.w = f2bf(o3);
            *(ushort4*)&D[16 * r + ln15][w * 64 + 16 * c + 4 * q] = u;
        }
    }
}

// ---- merged small chain: X[3200,K] -> L1 -> L2 -> P,Q  (one kernel) -------
__global__ __launch_bounds__(256, 4)
void mlp_pq(const float* __restrict__ Xf, int Kreal, int kcN, float xscale,
            const ushort_t* __restrict__ W1T, const float* __restrict__ b1,
            const ushort_t* __restrict__ W2T, const float* __restrict__ b2,
            const ushort_t* __restrict__ WPT, int wsPQ,
            const float* __restrict__ bP, ushort_t* __restrict__ Pout,
            const ushort_t* __restrict__ WQT, ushort_t* __restrict__ Qout)
{
    __shared__ ushort_t Abuf[32][264];
    __shared__ ushort_t Bbuf[32][264];
    const int tid = threadIdx.x;
    const int w = tid >> 6;
    const int l = tid & 63;
    const int ln15 = l & 15;
    const int q = l >> 4;
    const int klane = 8 * q;
    const int Rbase = blockIdx.x * 32;

    {
        int row = tid >> 3, seg = tid & 7;
        if (seg < kcN) {
            ushort_t tmp[32];
            const float* src = Xf + (size_t)(Rbase + row) * Kreal + seg * 32;
            #pragma unroll
            for (int u = 0; u < 32; ++u)
                tmp[u] = (seg * 32 + u < Kreal) ? f2bf(src[u] * xscale) : (ushort_t)0;
            #pragma unroll
            for (int u = 0; u < 4; ++u)
                *(uint4*)&Abuf[row][seg * 32 + u * 8] = *(uint4*)&tmp[u * 8];
        }
    }
    __syncthreads();

    f32x4 acc[2][4];
    gemm32(Abuf, W1T, 256, kcN, w, ln15, klane, acc);
    park32(Bbuf, acc, b1, 1, w, ln15, q);
    __syncthreads();
    gemm32(Bbuf, W2T, 256, 8, w, ln15, klane, acc);
    park32(Abuf, acc, b2, 1, w, ln15, q);
    __syncthreads();
    gemm32(Abuf, WPT, wsPQ, 8, w, ln15, klane, acc);
    park32(Bbuf, acc, bP, 0, w, ln15, q);
    __syncthreads();
    f32x4 acq[2][4];
    gemm32(Abuf, WQT, wsPQ, 8, w, ln15, klane, acq);
    #pragma unroll
    for (int m = 0; m < 4; ++m) {
        int ch = tid + m * 256;
        int row = ch >> 5;
        int o = (ch & 31) * 8;
        *(uint4*)&Pout[(size_t)(Rbase + row) * 256 + o] = *(const uint4*)&Bbuf[row][o];
    }
    __syncthreads();
    park32(Bbuf, acq, nullptr, 0, w, ln15, q);
    __syncthreads();
    #pragma unroll
    for (int m = 0; m < 4; ++m) {
        int ch = tid + m * 256;
        int row = ch >> 5;
        int o = (ch & 31) * 8;
        *(uint4*)&Qout[(size_t)(Rbase + row) * 256 + o] = *(const uint4*)&Bbuf[row][o];
    }
}

// ---- col-split 128-row GEMM core: acc[8][2] over As, wave w owns 32 cols --
__device__ __forceinline__ void gemm128cs(const ushort_t As[128][264],
                                          const ushort_t* __restrict__ WT,
                                          int wstr, int w, int ln15, int klane,
                                          f32x4 acc[8][2])
{
    #pragma unroll
    for (int r = 0; r < 8; ++r)
        #pragma unroll
        for (int c = 0; c < 2; ++c)
            acc[r][c][0] = acc[r][c][1] = acc[r][c][2] = acc[r][c][3] = 0.f;
    int wch[2];
    #pragma unroll
    for (int c = 0; c < 2; ++c) wch[c] = (w * 32 + 16 * c + ln15) * wstr;
    bf16x8 wf0[2];
    #pragma unroll
    for (int c = 0; c < 2; ++c)
        wf0[c] = *(const bf16x8*)(WT + wch[c] + klane);
    #pragma unroll
    for (int kc = 0; kc < 8; ++kc) {
        bf16x8 wf1[2];
        if (kc < 7) {
            #pragma unroll
            for (int c = 0; c < 2; ++c)
                wf1[c] = *(const bf16x8*)(WT + wch[c] + (kc + 1) * 32 + klane);
        }
        #pragma unroll
        for (int g = 0; g < 2; ++g) {       // 4-row halves: bound live af regs
            bf16x8 af[4];
            #pragma unroll
            for (int r = 0; r < 4; ++r)
                af[r] = *(const bf16x8*)&As[16 * (4 * g + r) + ln15][kc * 32 + klane];
            #pragma unroll
            for (int r = 0; r < 4; ++r)
                #pragma unroll
                for (int c = 0; c < 2; ++c)
                    acc[4 * g + r][c] = __builtin_amdgcn_mfma_f32_16x16x32_bf16(wf0[c], af[r], acc[4 * g + r][c], 0, 0, 0);
        }
        #pragma unroll
        for (int c = 0; c < 2; ++c) wf0[c] = wf1[c];
    }
}

// ---- edge kernel A (MLP2): 512 thr, col-split -----------------------------
__global__ __launch_bounds__(512, 4)
void edge_mlp2(const ushort_t* __restrict__ Pb, const ushort_t* __restrict__ Qb,
               const ushort_t* __restrict__ W2T,
               const float* __restrict__ b2,
               ushort_t* __restrict__ Y, float* __restrict__ aux)
{
    __shared__ ushort_t As[128][264];
    const int tid = threadIdx.x;
    const int w = tid >> 6;        // 0..7
    const int l = tid & 63;
    const int ln15 = l & 15;
    const int q = l >> 4;
    const int klane = 8 * q;
    const int Rbase = blockIdx.x * 128;

    // phase 1: hidden tile (512 threads cover 128 rows in one pass)
    {
        int row = tid >> 2;
        int R = Rbase + row;
        int b = R / E_EDGES;
        int e = R - b * E_EDGES;
        int i = e / 99;
        int k = e - 99 * i;
        int j = k + (k >= i ? 1 : 0);
        const ushort_t* prow = Pb + (size_t)(b * NNODE + j) * HID;
        const ushort_t* qrow = Qb + (size_t)(b * NNODE + i) * HID;
        int off = (tid & 3) * 8;
        uint4 pv[8], qv[8];
        #pragma unroll
        for (int u = 0; u < 8; ++u) {
            int o = off + u * 32;
            pv[u] = *(const uint4*)(prow + o);
            qv[u] = *(const uint4*)(qrow + o);
        }
        #pragma unroll
        for (int u = 0; u < 8; ++u) {
            int o = off + u * 32;
            union { uint4 v; ushort_t s[8]; } pu, qu, hu;
            pu.v = pv[u]; qu.v = qv[u];
            #pragma unroll
            for (int x = 0; x < 8; ++x)
                hu.s[x] = f2bf(elu_f(bf2f(pu.s[x]) + bf2f(qu.s[x])));
            *(uint4*)&As[row][o] = hu.v;
        }
    }
    __syncthreads();

    f32x4 acc[8][2];
    gemm128cs(As, W2T, 256, w, ln15, klane, acc);
    __syncthreads();

    // park x2 = ELU(acc + b2)
    #pragma unroll
    for (int c = 0; c < 2; ++c) {
        float4 bv = *(const float4*)&b2[w * 32 + 16 * c + 4 * q];
        #pragma unroll
        for (int r = 0; r < 8; ++r) {
            ushort4 u;
            u.x = f2bf(elu_f(acc[r][c][0] + bv.x));
            u.y = f2bf(elu_f(acc[r][c][1] + bv.y));
            u.z = f2bf(elu_f(acc[r][c][2] + bv.z));
            u.w = f2bf(elu_f(acc[r][c][3] + bv.w));
            *(ushort4*)&As[16 * r + ln15][w * 32 + 16 * c + 4 * q] = u;
        }
    }
    __syncthreads();

    #pragma unroll
    for (int m = 0; m < 8; ++m) {
        int ch = tid + m * 512;
        int row = ch >> 5;
        int o = (ch & 31) * 8;
        *(uint4*)&Y[((size_t)(Rbase + row)) * 256 + o] = *(const uint4*)&As[row][o];
    }

    if (tid < 64) {
        int c4 = tid * 4;
        int bn = Rbase / 99;
        int left = 99 - (Rbase - bn * 99);
        float s[4] = {0.f, 0.f, 0.f, 0.f};
        for (int r = 0; r < 128; ++r) {
            union { ushort4 v; ushort_t e[4]; } u;
            u.v = *(const ushort4*)&As[r][c4];
            #pragma unroll
            for (int g = 0; g < 4; ++g) s[g] += bf2f(u.e[g]);
            if (--left == 0) {
                #pragma unroll
                for (int g = 0; g < 4; ++g) {
                    atomicAdd(&aux[(size_t)bn * 256 + c4 + g], s[g]);
                    s[g] = 0.f;
                }
                ++bn; left = 99;
            }
        }
        #pragma unroll
        for (int g = 0; g < 4; ++g)
            atomicAdd(&aux[(size_t)bn * 256 + c4 + g], s[g]);
    }
}

// ---- edge kernel B (MLP4): 512 thr, col-split, R11 ordering ---------------
__global__ __launch_bounds__(512, 4)
void edge_mlp4(const ushort_t* __restrict__ Pb, const ushort_t* __restrict__ Qb,
               const ushort_t* __restrict__ X2,
               const ushort_t* __restrict__ WaT, int wsA,
               const ushort_t* __restrict__ WbT, int wsB,
               const float* __restrict__ b2,
               ushort_t* __restrict__ Y, ushort_t* __restrict__ pstat)
{
    __shared__ ushort_t As[128][264];
    const int tid = threadIdx.x;
    const int w = tid >> 6;
    const int l = tid & 63;
    const int ln15 = l & 15;
    const int q = l >> 4;
    const int klane = 8 * q;
    const int Rbase = blockIdx.x * 128;

    // stage x2 tile (batched, one pass with 512 threads)
    {
        int row = tid >> 2;
        const ushort_t* xrow = X2 + (size_t)(Rbase + row) * 256;
        int off = (tid & 3) * 8;
        uint4 xv[8];
        #pragma unroll
        for (int u = 0; u < 8; ++u) xv[u] = *(const uint4*)(xrow + off + u * 32);
        #pragma unroll
        for (int u = 0; u < 8; ++u) *(uint4*)&As[row][off + u * 32] = xv[u];
    }

    // gather offsets for the 8 row-tiles
    int oP[8], oQ[8];
    #pragma unroll
    for (int r = 0; r < 8; ++r) {
        int R = Rbase + 16 * r + ln15;
        int b = R / E_EDGES;
        int e = R - b * E_EDGES;
        int i = e / 99;
        int k = e - 99 * i;
        int j = k + (k >= i ? 1 : 0);
        oP[r] = (b * NNODE + j) * HID;
        oQ[r] = (b * NNODE + i) * HID;
    }
    __syncthreads();

    f32x4 acc[8][2];
    // L1 GEMM: acc = x2tile @ W4a3
    gemm128cs(As, WaT, wsA, w, ln15, klane, acc);
    __syncthreads();

    // hidden = ELU(acc + P[j] + Q[i]) -> As (batched per col-tile)
    #pragma unroll
    for (int c = 0; c < 2; ++c) {
        int ch = w * 32 + 16 * c + 4 * q;
        ushort4 pv[8], qv[8];
        #pragma unroll
        for (int r = 0; r < 8; ++r) {
            pv[r] = *(const ushort4*)(Pb + oP[r] + ch);
            qv[r] = *(const ushort4*)(Qb + oQ[r] + ch);
        }
        #pragma unroll
        for (int r = 0; r < 8; ++r) {
            union { ushort4 v; ushort_t s[4]; } pu, qu;
            pu.v = pv[r]; qu.v = qv[r];
            ushort4 u;
            u.x = f2bf(elu_f(acc[r][c][0] + bf2f(pu.s[0]) + bf2f(qu.s[0])));
            u.y = f2bf(elu_f(acc[r][c][1] + bf2f(pu.s[1]) + bf2f(qu.s[1])));
            u.z = f2bf(elu_f(acc[r][c][2] + bf2f(pu.s[2]) + bf2f(qu.s[2])));
            u.w = f2bf(elu_f(acc[r][c][3] + bf2f(pu.s[3]) + bf2f(qu.s[3])));
            *(ushort4*)&As[16 * r + ln15][ch] = u;
        }
    }
    __syncthreads();

    // L2 GEMM: acc = hidden @ W4b
    gemm128cs(As, WbT, wsB, w, ln15, klane, acc);
    __syncthreads();

    // x4 = ELU(acc + b2) -> As park
    #pragma unroll
    for (int c = 0; c < 2; ++c) {
        float4 bv = *(const float4*)&b2[w * 32 + 16 * c + 4 * q];
        #pragma unroll
        for (int r = 0; r < 8; ++r) {
            ushort4 u;
            u.x = f2bf(elu_f(acc[r][c][0] + bv.x));
            u.y = f2bf(elu_f(acc[r][c][1] + bv.y));
            u.z = f2bf(elu_f(acc[r][c][2] + bv.z));
            u.w = f2bf(elu_f(acc[r][c][3] + bv.w));
            *(ushort4*)&As[16 * r + ln15][w * 32 + 16 * c + 4 * q] = u;
        }
    }
    __syncthreads();

    #pragma unroll
    for (int m = 0; m < 8; ++m) {
        int ch = tid + m * 512;
        int row = ch >> 5;
        int o = (ch & 31) * 8;
        *(uint4*)&Y[((size_t)(Rbase + row)) * 256 + o] = *(const uint4*)&As[row][o];
    }

    if (tid < 64) {
        int c4 = tid * 4;
        float s[4] = {0.f, 0.f, 0.f, 0.f};
        float qq[4] = {0.f, 0.f, 0.f, 0.f};
        for (int r = 0; r < 128; ++r) {
            union { ushort4 v; ushort_t e[4]; } u;
            u.v = *(const ushort4*)&As[r][c4];
            #pragma unroll
            for (int g = 0; g < 4; ++g) {
                float v = bf2f(u.e[g]);
                s[g] += v;
                qq[g] = fmaf(v, v, qq[g]);
            }
        }
        size_t base = (size_t)blockIdx.x * 512;
        ushort4 us, uq;
        us.x = f2bf(s[0]);  us.y = f2bf(s[1]);  us.z = f2bf(s[2]);  us.w = f2bf(s[3]);
        uq.x = f2bf(qq[0]); uq.y = f2bf(qq[1]); uq.z = f2bf(qq[2]); uq.w = f2bf(qq[3]);
        *(ushort4*)&pstat[base + c4]       = us;
        *(ushort4*)&pstat[base + 256 + c4] = uq;
    }
}

// ---- reduce per-block partials -> stats -----------------------------------
__global__ __launch_bounds__(256)
void reduce_stats(const ushort_t* __restrict__ pstat, float* __restrict__ stats)
{
    int c = threadIdx.x;
    float s = 0.f, q = 0.f;
    for (int b = blockIdx.x; b < NBLK2; b += 64) {
        size_t base = (size_t)b * 512;
        s += bf2f(pstat[base + c]);
        q += bf2f(pstat[base + 256 + c]);
    }
    atomicAdd(&stats[c], s);
    atomicAdd(&stats[256 + c], q);
}

// ---- fold BN + fc into Wfold[256][2], bfold[2] ----------------------------
__global__ __launch_bounds__(256)
void fold_kernel(const float* __restrict__ stats,
                 const float* __restrict__ gamma, const float* __restrict__ beta,
                 const float* __restrict__ fcW, const float* __restrict__ fcb,
                 float* __restrict__ fold)
{
    __shared__ float red0[256], red1[256];
    int c = threadIdx.x;
    float mean  = stats[c] * (1.f / M_BIG);
    float var   = stats[256 + c] * (1.f / M_BIG) - mean * mean;
    float inv   = rsqrtf(var + 1e-5f);
    float scale = inv * gamma[c];
    float sh    = beta[c] - mean * scale;
    float w0 = fcW[c * 2 + 0], w1 = fcW[c * 2 + 1];
    fold[c * 2 + 0] = scale * w0;
    fold[c * 2 + 1] = scale * w1;
    red0[c] = sh * w0;
    red1[c] = sh * w1;
    __syncthreads();
    for (int off = 128; off > 0; off >>= 1) {
        if (c < off) { red0[c] += red0[c + off]; red1[c] += red1[c + off]; }
        __syncthreads();
    }
    if (c == 0) {
        fold[512] = red0[0] + fcb[0];
        fold[513] = red1[0] + fcb[1];
    }
}

// ---- final: out[R][2] = x4_row . Wfold + bfold ----------------------------
__global__ __launch_bounds__(256)
void final_kernel(const ushort_t* __restrict__ x4, const float* __restrict__ fold,
                  float* __restrict__ out)
{
    int tid  = threadIdx.x;
    int l32  = tid & 31;
    int g    = tid >> 5;
    int R = blockIdx.x * 8 + g;
    int c0 = l32 * 8;
    union { uint4 qv; ushort_t s[8]; } u;
    u.qv = *(const uint4*)(x4 + (size_t)R * 256 + c0);
    float a0 = 0.f, a1 = 0.f;
    #pragma unroll
    for (int j = 0; j < 8; ++j) {
        float v = bf2f(u.s[j]);
        a0 = fmaf(v, fold[(c0 + j) * 2 + 0], a0);
        a1 = fmaf(v, fold[(c0 + j) * 2 + 1], a1);
    }
    #pragma unroll
    for (int off = 16; off > 0; off >>= 1) {
        a0 += __shfl_down(a0, off);
        a1 += __shfl_down(a1, off);
    }
    if (l32 == 0) {
        out[(size_t)R * 2 + 0] = a0 + fold[512];
        out[(size_t)R * 2 + 1] = a1 + fold[513];
    }
}

extern "C" void kernel_launch(void* const* d_in, const int* in_sizes, int n_in,
                              void* d_out, int out_size, void* d_ws, size_t ws_size,
                              hipStream_t stream)
{
    (void)in_sizes; (void)n_in; (void)out_size; (void)ws_size;

    const float* inputs = (const float*)d_in[0];
    const float* m1W1 = (const float*)d_in[3];
    const float* m1b1 = (const float*)d_in[4];
    const float* m1W2 = (const float*)d_in[5];
    const float* m1b2 = (const float*)d_in[6];
    const float* m2W1 = (const float*)d_in[7];
    const float* m2b1 = (const float*)d_in[8];
    const float* m2W2 = (const float*)d_in[9];
    const float* m2b2 = (const float*)d_in[10];
    const float* m3W1 = (const float*)d_in[11];
    const float* m3b1 = (const float*)d_in[12];
    const float* m3W2 = (const float*)d_in[13];
    const float* m3b2 = (const float*)d_in[14];
    const float* m4W1 = (const float*)d_in[15];
    const float* m4b1 = (const float*)d_in[16];
    const float* m4W2 = (const float*)d_in[17];
    const float* m4b2 = (const float*)d_in[18];
    const float* gamma = (const float*)d_in[19];
    const float* beta  = (const float*)d_in[20];
    const float* fcW   = (const float*)d_in[21];
    const float* fcb   = (const float*)d_in[22];
    float* out = (float*)d_out;

    // ---- workspace layout ----
    char* ws = (char*)d_ws;
    const size_t BIGB = (size_t)M_BIG * 256 * 2;      // 162,201,600
    const size_t HB   = (size_t)M_SMALL * 256 * 2;    // 1,638,400
    const size_t SM4  = (size_t)M_SMALL * 256 * 4;    // 3,276,800
    ushort_t* bigX     = (ushort_t*)ws;                         // x2 then x4
    ushort_t* pstat    = (ushort_t*)(ws + BIGB);                // 2.53 MB
    float*    incoming = (float*)(ws + BIGB + 2 * HB);
    ushort_t* Pbuf     = (ushort_t*)(ws + BIGB + 2 * HB + SM4);
    ushort_t* Qbuf     = (ushort_t*)(ws + BIGB + 3 * HB + SM4);
    float*    stats    = (float*)(ws + BIGB + 4 * HB + SM4);
    float*    fold     = stats + 512;
    ushort_t* w1t      = (ushort_t*)(ws + BIGB + 4 * HB + SM4 + 8192);
    ushort_t* w1bt     = w1t  + 256 * 256;
    ushort_t* w2pt     = w1bt + 256 * 256;     // [256][512]
    ushort_t* w2t      = w2pt + 256 * 512;
    ushort_t* w3at     = w2t  + 256 * 256;
    ushort_t* w3bt     = w3at + 256 * 256;
    ushort_t* w4pt     = w3bt + 256 * 256;     // [256][768]
    ushort_t* w4bt     = w4pt + 256 * 768;

    hipMemsetAsync(stats, 0, 2048, stream);
    hipMemsetAsync(incoming, 0, SM4, stream);

    dim3 blk(256);
    dim3 blk512(512);
    wcvt_all<<<176, blk, 0, stream>>>(m1W1, m1W2, m2W1, m2W2, m3W1, m3W2, m4W1, m4W2,
                                      w1t, w1bt, w2pt, w2t, w3at, w3bt, w4pt, w4bt);
    // MLP1 + PQ2 (h1 never leaves LDS)
    mlp_pq<<<100, blk, 0, stream>>>(inputs, 200, 7, 1.f,
                                    w1t, m1b1, w1bt, m1b2,
                                    w2pt, 512, m2b1, Pbuf,
                                    w2pt + 256, Qbuf);
    // edge MLP2 -> x2 + e2n sums
    edge_mlp2<<<NBLK2, blk512, 0, stream>>>(Pbuf, Qbuf, w2t, m2b2, bigX, incoming);
    // MLP3 + PQ4
    mlp_pq<<<100, blk, 0, stream>>>(incoming, 256, 8, 1.f / 9900.f,
                                    w3at, m3b1, w3bt, m3b2,
                                    w4pt, 768, m4b1, Pbuf,
                                    w4pt + 256, Qbuf);
    // edge MLP4 (skip weight = w4pt cols 512.., stride 768)
    edge_mlp4<<<NBLK2, blk512, 0, stream>>>(Pbuf, Qbuf, bigX,
                                            w4pt + 512, 768, w4bt, 256,
                                            m4b2, bigX, pstat);
    reduce_stats<<<64, blk, 0, stream>>>(pstat, stats);
    fold_kernel<<<1, blk, 0, stream>>>(stats, gamma, beta, fcW, fcb, fold);
    final_kernel<<<M_BIG / 8, blk, 0, stream>>>(bigX, fold, out);
}